// Round 15
// baseline (1146.072 us; speedup 1.0000x reference)
//
#include <hip/hip_runtime.h>

#define DM 512
#define NST 16
#define NDEPTH 8
#define NB 2
#define NL 1024
#define MROWS 2048
#define VOCAB 50257
#define VPAD  50304
#define NCH 32     // chunks along L
#define CLEN 32    // steps per chunk

typedef __attribute__((ext_vector_type(8))) short bf16x8;
typedef __attribute__((ext_vector_type(4))) float f32x4;
typedef __attribute__((ext_vector_type(8))) unsigned short ushort8;

#define AS1(p) ((const __attribute__((address_space(1))) void*)(p))
#define AS3(p) ((__attribute__((address_space(3))) void*)(p))

static __device__ __forceinline__ unsigned short f2bf(float f) {
  unsigned int x = __float_as_uint(f);
  unsigned int r = (x + 0x7FFFu + ((x >> 16) & 1u)) >> 16;
  return (unsigned short)r;
}
static __device__ __forceinline__ float bf2f(unsigned short u) {
  return __uint_as_float((unsigned int)u << 16);
}

// ---------------- embedding gather: x[b,l,:] = emb[id] (fp32) ----------------
__global__ __launch_bounds__(256) void k_gather(const int* __restrict__ ids,
    const float* __restrict__ emb, float* __restrict__ x)
{
  int gid = blockIdx.x * 256 + threadIdx.x;      // one float4 each, 2048*128
  int row = gid >> 7, c = (gid & 127) * 4;
  int id = ids[row];
  *(float4*)(x + (size_t)row * DM + c) = *(const float4*)(emb + (size_t)id * DM + c);
}

// ---------------- weight transpose+bf16: Wt[n][k] = bf16(W[k][n]) ------------
// f: 0=W_dt (into Tdtbc rows 0-511), 1..3=W_r/k/v (Trkv), 4=W_o (To)
__global__ void k_transpose(const float* __restrict__ Wdt, const float* __restrict__ Wr,
    const float* __restrict__ Wk, const float* __restrict__ Wv, const float* __restrict__ Wo,
    unsigned short* __restrict__ Tdtbc, unsigned short* __restrict__ Trkv, unsigned short* __restrict__ To)
{
  __shared__ float tile[32][33];
  int z = blockIdx.z, layer = z / 5, f = z % 5;
  const float* src;
  unsigned short* dst;
  size_t lw = (size_t)layer * DM * DM;
  if (f == 0)      { src = Wdt + lw; dst = Tdtbc + (size_t)layer * 640 * DM; }
  else if (f == 1) { src = Wr  + lw; dst = Trkv + (size_t)layer * 3 * DM * DM; }
  else if (f == 2) { src = Wk  + lw; dst = Trkv + (size_t)layer * 3 * DM * DM + DM * DM; }
  else if (f == 3) { src = Wv  + lw; dst = Trkv + (size_t)layer * 3 * DM * DM + 2 * DM * DM; }
  else             { src = Wo  + lw; dst = To   + lw; }
  int tx = threadIdx.x, ty = threadIdx.y;        // 32 x 8
  int kb = blockIdx.y * 32, nb = blockIdx.x * 32;
  #pragma unroll
  for (int i = 0; i < 4; i++)
    tile[ty + i * 8][tx] = src[(size_t)(kb + ty + i * 8) * DM + nb + tx];
  __syncthreads();
  #pragma unroll
  for (int i = 0; i < 4; i++)
    dst[(size_t)(nb + ty + i * 8) * DM + kb + tx] = f2bf(tile[tx][ty + i * 8]);
}

// -------- pack W_B|W_C transposed into Tdtbc rows 512-639 (32 real + pad) ----
__global__ __launch_bounds__(256) void k_bcpack(const float* __restrict__ WB,
    const float* __restrict__ WC, unsigned short* __restrict__ Tdtbc)
{
  int gid = blockIdx.x * 256 + threadIdx.x;      // ((layer*128)+n)*512+k
  int k = gid & 511, n = (gid >> 9) & 127, layer = gid >> 16;
  float v = 0.f;
  if (n < 16)      v = WB[((size_t)layer * DM + k) * NST + n];
  else if (n < 32) v = WC[((size_t)layer * DM + k) * NST + (n - 16)];
  Tdtbc[(size_t)layer * 640 * DM + (size_t)(512 + n) * DM + k] = f2bf(v);
}

// ---------------- emb -> bf16, padded rows zero ------------------------------
__global__ __launch_bounds__(256) void k_embcvt(const float* __restrict__ emb,
    unsigned short* __restrict__ out)
{
  int gid = blockIdx.x * 256 + threadIdx.x;      // 8 elements each
  size_t base = (size_t)gid * 8;
  int row = (int)(base >> 9);
  ushort8 o;
  if (row < VOCAB) {
    float4 a = *(const float4*)(emb + base);
    float4 b = *(const float4*)(emb + base + 4);
    o[0]=f2bf(a.x); o[1]=f2bf(a.y); o[2]=f2bf(a.z); o[3]=f2bf(a.w);
    o[4]=f2bf(b.x); o[5]=f2bf(b.y); o[6]=f2bf(b.z); o[7]=f2bf(b.w);
  } else {
    o = (ushort8)0;
  }
  *(ushort8*)(out + base) = o;
}

// ---------------- LayerNorm: wave per row, optional f32 + bf16 outputs -------
__global__ __launch_bounds__(256) void k_ln(const float* __restrict__ x,
    const float* __restrict__ g, const float* __restrict__ bb,
    float* __restrict__ of, unsigned short* __restrict__ ob)
{
  const int w = threadIdx.x >> 6, l = threadIdx.x & 63;
  const int row = blockIdx.x * 4 + w;
  const float* xr = x + (size_t)row * DM + l * 8;
  float4 v0 = *(const float4*)(xr);
  float4 v1 = *(const float4*)(xr + 4);
  float s = v0.x + v0.y + v0.z + v0.w + v1.x + v1.y + v1.z + v1.w;
  float q = v0.x*v0.x + v0.y*v0.y + v0.z*v0.z + v0.w*v0.w
          + v1.x*v1.x + v1.y*v1.y + v1.z*v1.z + v1.w*v1.w;
  #pragma unroll
  for (int m = 1; m < 64; m <<= 1) { s += __shfl_xor(s, m); q += __shfl_xor(q, m); }
  const float mu = s * (1.0f / DM);
  const float var = q * (1.0f / DM) - mu * mu;
  const float rs = rsqrtf(var + 1e-5f);
  const float4 g0 = *(const float4*)(g + l * 8);
  const float4 g1 = *(const float4*)(g + l * 8 + 4);
  const float4 b0 = *(const float4*)(bb + l * 8);
  const float4 b1 = *(const float4*)(bb + l * 8 + 4);
  float y[8];
  y[0] = (v0.x - mu) * rs * g0.x + b0.x;
  y[1] = (v0.y - mu) * rs * g0.y + b0.y;
  y[2] = (v0.z - mu) * rs * g0.z + b0.z;
  y[3] = (v0.w - mu) * rs * g0.w + b0.w;
  y[4] = (v1.x - mu) * rs * g1.x + b1.x;
  y[5] = (v1.y - mu) * rs * g1.y + b1.y;
  y[6] = (v1.z - mu) * rs * g1.z + b1.z;
  y[7] = (v1.w - mu) * rs * g1.w + b1.w;
  if (of) {
    float4 o0 = {y[0], y[1], y[2], y[3]}, o1 = {y[4], y[5], y[6], y[7]};
    *(float4*)(of + (size_t)row * DM + l * 8) = o0;
    *(float4*)(of + (size_t)row * DM + l * 8 + 4) = o1;
  }
  if (ob) {
    ushort8 o;
    #pragma unroll
    for (int j = 0; j < 8; j++) o[j] = f2bf(y[j]);
    *(ushort8*)(ob + (size_t)row * DM + l * 8) = o;
  }
}

// == GEMM: overlapped double-buffer 2-phase (r13 proven), BK=64, XOR swizzle ==
// STAGE(t+1) issued BEFORE COMPUTE(t); plain __syncthreads per tile (drain is
// cheap: compute covers the load latency). Statically distinct buffers.
// EPI: 0 plain | 2 C2 += 0.5*acc | 3 fused dt(softplus+bias)/BC
//      4 HEAD: 1D XCD-ownership grid (XCD c owns n-tiles [c*50,c*50+50),
//              m innermost), n<VOCAB guard, ldc=VOCAB.
template<int BM, int BN, int EPI>
__global__ __launch_bounds__(256) void gemm_bt(const unsigned short* __restrict__ A,
    const unsigned short* __restrict__ Bt, float* __restrict__ C, int N, int ldc,
    const float* __restrict__ bias, float* __restrict__ C2)
{
  constexpr int K = DM;
  constexpr int MI = BM / 32, NI = BN / 32;
  __shared__ unsigned short lsA0[BM * 64];
  __shared__ unsigned short lsA1[BM * 64];
  __shared__ unsigned short lsB0[BN * 64];
  __shared__ unsigned short lsB1[BN * 64];
  const int t = threadIdx.x;
  const int w = t >> 6, l = t & 63;
  const int wm = (w >> 1) * (BM / 2), wn = (w & 1) * (BN / 2);
  size_t bm, bn;
  if constexpr (EPI == 4) {
    const int c = (int)blockIdx.x & 7, j = (int)blockIdx.x >> 3;
    const int ntile = c * 50 + (j >> 4), mtile = j & 15;
    if (ntile >= 393) return;                   // 50304/128 = 393 real n-tiles
    bm = (size_t)mtile * BM; bn = (size_t)ntile * BN;
  } else {
    bm = (size_t)blockIdx.x * BM; bn = (size_t)blockIdx.y * BN;
  }
  f32x4 acc[MI][NI] = {};
  const int srow = t >> 3, sslot = t & 7;       // stage: 32 rows x 8 slots per op
  const int gs = sslot ^ (srow & 7);            // pre-swizzled source slot
  const unsigned short* Ag = A + (bm + srow) * K + gs * 8;
  const unsigned short* Bg = Bt + (bn + srow) * K + gs * 8;
  const int lr = l & 15, lq = l >> 4;

#define GB_STAGE(dA, dB, kt) do {                                              \
    const int k0_ = (kt) * 64;                                                 \
    _Pragma("unroll")                                                          \
    for (int o = 0; o < BM / 32; ++o)                                          \
      __builtin_amdgcn_global_load_lds(AS1(Ag + (size_t)(o * 32) * K + k0_),   \
          AS3(dA + (o * 32 + srow) * 64 + sslot * 8), 16, 0, 0);               \
    _Pragma("unroll")                                                          \
    for (int o = 0; o < BN / 32; ++o)                                          \
      __builtin_amdgcn_global_load_lds(AS1(Bg + (size_t)(o * 32) * K + k0_),   \
          AS3(dB + (o * 32 + srow) * 64 + sslot * 8), 16, 0, 0);               \
  } while (0)

#define GB_COMPUTE(sA, sB) do {                                                \
    bf16x8 af[MI][2], bfr[NI][2];                                              \
    _Pragma("unroll")                                                          \
    for (int i = 0; i < MI; ++i) {                                             \
      int row = wm + i * 16 + lr;                                              \
      _Pragma("unroll")                                                        \
      for (int h = 0; h < 2; ++h)                                              \
        af[i][h] = *(const bf16x8*)(sA + row * 64 + (((h * 4 + lq) ^ (row & 7)) * 8)); \
    }                                                                          \
    _Pragma("unroll")                                                          \
    for (int i = 0; i < NI; ++i) {                                             \
      int row = wn + i * 16 + lr;                                              \
      _Pragma("unroll")                                                        \
      for (int h = 0; h < 2; ++h)                                              \
        bfr[i][h] = *(const bf16x8*)(sB + row * 64 + (((h * 4 + lq) ^ (row & 7)) * 8)); \
    }                                                                          \
    _Pragma("unroll")                                                          \
    for (int h = 0; h < 2; ++h)                                                \
      _Pragma("unroll")                                                        \
      for (int mi = 0; mi < MI; ++mi)                                          \
        _Pragma("unroll")                                                      \
        for (int ni = 0; ni < NI; ++ni)                                        \
          acc[mi][ni] = __builtin_amdgcn_mfma_f32_16x16x32_bf16(af[mi][h], bfr[ni][h], acc[mi][ni], 0, 0, 0); \
  } while (0)

  GB_STAGE(lsA0, lsB0, 0);
  __syncthreads();                              // buf0 ready (implicit vmcnt(0))
  #pragma unroll
  for (int kk = 0; kk < 4; ++kk) {
    GB_STAGE(lsA1, lsB1, kk * 2 + 1);           // loads fly under compute
    GB_COMPUTE(lsA0, lsB0);
    __syncthreads();                            // buf1 ready; buf0 reads done
    if (kk * 2 + 2 < 8) GB_STAGE(lsA0, lsB0, kk * 2 + 2);
    GB_COMPUTE(lsA1, lsB1);
    __syncthreads();                            // buf0 ready; buf1 reads done
  }
#undef GB_STAGE
#undef GB_COMPUTE

  const int lg = l >> 4;
  #pragma unroll
  for (int mi = 0; mi < MI; ++mi) {
    #pragma unroll
    for (int ni = 0; ni < NI; ++ni) {
      int n = (int)bn + wn + ni * 16 + lr;
      if (EPI == 4 && n >= VOCAB) continue;
      size_t m0 = bm + wm + mi * 16 + lg * 4;
      #pragma unroll
      for (int j = 0; j < 4; ++j) {
        float v = acc[mi][ni][j];
        if (EPI == 0 || EPI == 4) {
          C[(m0 + j) * (size_t)ldc + n] = v;
        } else if (EPI == 2) {
          C2[(m0 + j) * (size_t)ldc + n] += 0.5f * v;
        } else {                                // fused dt | BC
          if (n < 512) {
            float b = v + bias[n];
            C[(m0 + j) * (size_t)512 + n] = fmaxf(b, 0.f) + log1pf(__expf(-fabsf(b)));
          } else if (n < 544) {
            C2[(m0 + j) * (size_t)32 + (n - 512)] = v;
          }
        }
      }
    }
  }
}

// ============================ chunked SSM scan ===============================
__global__ __launch_bounds__(256) void k_ssm1(const float* __restrict__ dt,
    const unsigned short* __restrict__ u, const float* __restrict__ BC,
    const float* __restrict__ A_log, float* __restrict__ Pb, float* __restrict__ Sb)
{
  const int t = threadIdx.x;
  const int grp = t >> 4, n = t & 15;
  const int cg = blockIdx.x & 63, ck = blockIdx.x >> 6;   // channel-group, chunk
  const int ch = cg * 16 + grp;                           // 0..1023
  const int b = ch >> 9, d = ch & 511;
  const float A = -__expf(A_log[d * NST + n]);
  const int t0 = ck * CLEN;
  const float* dtp = dt + ((size_t)b * NL + t0) * DM + d;
  const unsigned short* up = u + ((size_t)b * NL + t0) * DM + d;
  const float* bcp = BC + ((size_t)b * NL + t0) * 32 + n;
  float P = 1.f, S = 0.f;
  #pragma unroll
  for (int tt = 0; tt < CLEN; ++tt) {
    float dtv = dtp[(size_t)tt * DM];
    float uv  = bf2f(up[(size_t)tt * DM]);
    float Bv  = bcp[(size_t)tt * 32];
    float e = __expf(dtv * A);
    S = fmaf(e, S, dtv * uv * Bv);
    P *= e;
  }
  size_t cn = (size_t)ch * NST + n;                       // 0..16383
  Pb[cn * NCH + ck] = P;
  Sb[cn * NCH + ck] = S;
}

__global__ __launch_bounds__(256) void k_ssm2(const float* __restrict__ Pb,
    const float* __restrict__ Sb, float* __restrict__ H0)
{
  const int wid = blockIdx.x * 8 + (threadIdx.x >> 5);    // channel-state 0..16383
  const int lane = threadIdx.x & 31;                      // chunk
  float coef = Pb[(size_t)wid * NCH + lane];
  float sum  = Sb[(size_t)wid * NCH + lane];
  #pragma unroll
  for (int m = 1; m < 32; m <<= 1) {
    float cr = __shfl_up(coef, m, 32);
    float sr = __shfl_up(sum, m, 32);
    if (lane >= m) { sum = fmaf(coef, sr, sum); coef *= cr; }
  }
  float hp = __shfl_up(sum, 1, 32);
  H0[(size_t)wid * NCH + lane] = (lane == 0) ? 0.f : hp;  // h at chunk entry
}

__global__ __launch_bounds__(256) void k_ssm3(const float* __restrict__ dt,
    const unsigned short* __restrict__ u, const float* __restrict__ BC,
    const float* __restrict__ A_log, const float* __restrict__ Dp,
    const float* __restrict__ H0, float* __restrict__ x)
{
  const int t = threadIdx.x;
  const int grp = t >> 4, n = t & 15;
  const int cg = blockIdx.x & 63, ck = blockIdx.x >> 6;
  const int ch = cg * 16 + grp;
  const int b = ch >> 9, d = ch & 511;
  const float A = -__expf(A_log[d * NST + n]);
  const float Dpv = Dp[d];
  const int t0 = ck * CLEN;
  const float* dtp = dt + ((size_t)b * NL + t0) * DM + d;
  const unsigned short* up = u + ((size_t)b * NL + t0) * DM + d;
  const float* bcp = BC + ((size_t)b * NL + t0) * 32 + n;
  float* xp = x + ((size_t)b * NL + t0) * DM + d;
  size_t cn = (size_t)ch * NST + n;
  float h = H0[cn * NCH + ck];
  #pragma unroll
  for (int tt = 0; tt < CLEN; ++tt) {
    float dtv = dtp[(size_t)tt * DM];
    float uv  = bf2f(up[(size_t)tt * DM]);
    float Bv  = bcp[(size_t)tt * 32];
    float Cv  = bcp[(size_t)tt * 32 + 16];
    float e = __expf(dtv * A);
    h = fmaf(e, h, dtv * uv * Bv);
    float p2 = h * Cv;
    p2 += __shfl_xor(p2, 1);
    p2 += __shfl_xor(p2, 2);
    p2 += __shfl_xor(p2, 4);
    p2 += __shfl_xor(p2, 8);
    if (n == 0) xp[(size_t)tt * DM] += 0.5f * (p2 + Dpv * uv);
  }
}

// ============================ chunked WKV scan ===============================
__global__ __launch_bounds__(256) void k_wkv1(const float* __restrict__ rkv,
    const float* __restrict__ tdec, float* __restrict__ SaB, float* __restrict__ SbB)
{
  const int gid = blockIdx.x * 256 + threadIdx.x;         // 32768
  const int ch = gid & 1023, ck = gid >> 10;
  const int b = ch >> 9, d = ch & 511;
  const float w = __expf(-__expf(tdec[d]));
  const float* base = rkv + ((size_t)b * NL + ck * CLEN) * 1536;
  float Sa = 0.f, Sb = 0.f;
  #pragma unroll
  for (int tt = 0; tt < CLEN; ++tt) {
    const float* row = base + (size_t)tt * 1536;
    float kt = row[512 + d];
    kt = fminf(30.f, fmaxf(-30.f, kt));
    float vt = row[1024 + d];
    float ek = __expf(kt);
    Sa = fmaf(w, Sa, ek * vt);
    Sb = fmaf(w, Sb, ek);
  }
  SaB[(size_t)ch * NCH + ck] = Sa;
  SbB[(size_t)ch * NCH + ck] = Sb;
}

__global__ __launch_bounds__(256) void k_wkv2(const float* __restrict__ SaB,
    const float* __restrict__ SbB, const float* __restrict__ tdec,
    float* __restrict__ HaB, float* __restrict__ HbB)
{
  const int ch = blockIdx.x * 8 + (threadIdx.x >> 5);     // 0..1023
  const int lane = threadIdx.x & 31;                      // chunk
  const int d = ch & 511;
  float coef = __expf(-32.f * __expf(tdec[d]));           // w^CLEN
  float sa = SaB[(size_t)ch * NCH + lane];
  float sb = SbB[(size_t)ch * NCH + lane];
  #pragma unroll
  for (int m = 1; m < 32; m <<= 1) {
    float cr  = __shfl_up(coef, m, 32);
    float sar = __shfl_up(sa, m, 32);
    float sbr = __shfl_up(sb, m, 32);
    if (lane >= m) { sa = fmaf(coef, sar, sa); sb = fmaf(coef, sbr, sb); coef *= cr; }
  }
  float ha = __shfl_up(sa, 1, 32);
  float hb = __shfl_up(sb, 1, 32);
  HaB[(size_t)ch * NCH + lane] = (lane == 0) ? 0.f : ha;
  HbB[(size_t)ch * NCH + lane] = (lane == 0) ? 0.f : hb;
}

__global__ __launch_bounds__(256) void k_wkv3(const float* __restrict__ rkv,
    const float* __restrict__ tdec, const float* __restrict__ tfir,
    const float* __restrict__ HaB, const float* __restrict__ HbB,
    unsigned short* __restrict__ ro)
{
  const int gid = blockIdx.x * 256 + threadIdx.x;         // 32768
  const int ch = gid & 1023, ck = gid >> 10;
  const int b = ch >> 9, d = ch & 511;
  const float w = __expf(-__expf(tdec[d]));
  const float tf = tfir[d];
  float a = HaB[(size_t)ch * NCH + ck];
  float bden = HbB[(size_t)ch * NCH + ck];
  const int t0 = ck * CLEN;
  const float* base = rkv + ((size_t)b * NL + t0) * 1536;
  unsigned short* rop = ro + ((size_t)b * NL + t0) * DM + d;
  #pragma unroll
  for (int tt = 0; tt < CLEN; ++tt) {
    const float* row = base + (size_t)tt * 1536;
    float rv = row[d];
    float kt = row[512 + d];
    kt = fminf(30.f, fmaxf(-30.f, kt));
    float vt = row[1024 + d];
    float ek = __expf(kt);
    float eu = __expf(tf + kt);
    float out = __fdividef(a + eu * vt, bden + eu + 1e-6f);
    float sig = __fdividef(1.f, 1.f + __expf(-rv));
    rop[(size_t)tt * DM] = f2bf(sig * out);
    a = fmaf(w, a, ek * vt);
    bden = fmaf(w, bden, ek);
  }
}

// ============================================================================
extern "C" void kernel_launch(void* const* d_in, const int* in_sizes, int n_in,
                              void* d_out, int out_size, void* d_ws, size_t ws_size,
                              hipStream_t stream)
{
  const int*   ids   = (const int*)d_in[0];
  const float* emb   = (const float*)d_in[1];
  const float* ln1_g = (const float*)d_in[2];
  const float* ln1_b = (const float*)d_in[3];
  const float* W_dt  = (const float*)d_in[4];
  const float* b_dt  = (const float*)d_in[5];
  const float* W_B   = (const float*)d_in[6];
  const float* W_C   = (const float*)d_in[7];
  const float* A_log = (const float*)d_in[8];
  const float* D_p   = (const float*)d_in[9];
  const float* ln2_g = (const float*)d_in[10];
  const float* ln2_b = (const float*)d_in[11];
  const float* W_r   = (const float*)d_in[12];
  const float* W_k   = (const float*)d_in[13];
  const float* W_v   = (const float*)d_in[14];
  const float* W_o   = (const float*)d_in[15];
  const float* t_dec = (const float*)d_in[16];
  const float* t_fir = (const float*)d_in[17];
  const float* lnf_g = (const float*)d_in[18];
  const float* lnf_b = (const float*)d_in[19];

  char* p = (char*)d_ws;
  float*          xres  = (float*)(p + 0);                       // 4 MB
  float*          dtb   = (float*)(p + 8388608);                 // 4 MB
  float*          rkv   = (float*)(p + 12582912);                // 12 MB
  float*          BCb   = (float*)(p + 25165824);                // 256 KB
  unsigned short* abuf  = (unsigned short*)(p + 25427968);       // 2 MB
  unsigned short* Tdtbc = (unsigned short*)(p + 27525120);       // 5 MB (8 x 640 x 512)
  unsigned short* To    = (unsigned short*)(p + 32768000);       // 4 MB
  unsigned short* Trkv  = (unsigned short*)(p + 36962304);       // 12 MB
  unsigned short* Tem   = (unsigned short*)(p + 49545216);       // 51.5 MB

  // scan scratch reuses idle regions (NCH=32):
  float* Pb  = rkv;                           // 2 MB  (rkv idle during SSM)
  float* Sb  = rkv + 524288;                  // 2 MB
  float* H0  = rkv + 1048576;                 // 2 MB
  float* SaB = dtb;                           // 128 KB each (dtb idle during WKV)
  float* SbB = dtb + 32768;
  float* HaB = dtb + 65536;
  float* HbB = dtb + 98304;

  // ---- prep ----
  k_gather<<<1024, 256, 0, stream>>>(ids, emb, xres);
  k_transpose<<<dim3(16, 16, 40), dim3(32, 8), 0, stream>>>(W_dt, W_r, W_k, W_v, W_o, Tdtbc, Trkv, To);
  k_bcpack<<<2048, 256, 0, stream>>>(W_B, W_C, Tdtbc);
  k_embcvt<<<12576, 256, 0, stream>>>(emb, Tem);

  // ---- layers ----
  for (int i = 0; i < NDEPTH; ++i) {
    k_ln<<<512, 256, 0, stream>>>(xres, ln1_g + i * DM, ln1_b + i * DM, nullptr, abuf);
    // fused: dt = softplus(u@W_dt + b_dt), BC = u@[W_B|W_C]
    gemm_bt<64, 128, 3><<<dim3(32, 5), 256, 0, stream>>>(abuf,
        Tdtbc + (size_t)i * 640 * DM, dtb, 640, 512, b_dt + i * DM, BCb);
    // chunk-parallel SSM scan (u read as bf16 from abuf)
    k_ssm1<<<2048, 256, 0, stream>>>(dtb, abuf, BCb, A_log + (size_t)i * DM * NST, Pb, Sb);
    k_ssm2<<<2048, 256, 0, stream>>>(Pb, Sb, H0);
    k_ssm3<<<2048, 256, 0, stream>>>(dtb, abuf, BCb, A_log + (size_t)i * DM * NST,
        D_p + i * DM, H0, xres);
    k_ln<<<512, 256, 0, stream>>>(xres, ln2_g + i * DM, ln2_b + i * DM, nullptr, abuf);
    gemm_bt<64, 128, 0><<<dim3(32, 12), 256, 0, stream>>>(abuf,
        Trkv + (size_t)i * 3 * DM * DM, rkv, 1536, 1536, nullptr, nullptr);
    // chunk-parallel WKV scan
    k_wkv1<<<128, 256, 0, stream>>>(rkv, t_dec + i * DM, SaB, SbB);
    k_wkv2<<<128, 256, 0, stream>>>(SaB, SbB, t_dec + i * DM, HaB, HbB);
    k_wkv3<<<128, 256, 0, stream>>>(rkv, t_dec + i * DM, t_fir + i * DM, HaB, HbB, abuf);
    gemm_bt<64, 128, 2><<<dim3(32, 4), 256, 0, stream>>>(abuf,
        To + (size_t)i * DM * DM, nullptr, 512, 512, nullptr, xres);
  }

  // ---- final LN + tied head ----
  // head: overlapped-dbuf 128x128, 1D XCD-ownership grid (8 x 800 blocks)
  k_ln<<<512, 256, 0, stream>>>(xres, lnf_g, lnf_b, nullptr, abuf);
  gemm_bt<128, 128, 4><<<6400, 256, 0, stream>>>(abuf, Tem, (float*)d_out,
      VOCAB, VOCAB, nullptr, nullptr);
}

// Round 16
// 1109.959 us; speedup vs baseline: 1.0325x; 1.0325x over previous
//
#include <hip/hip_runtime.h>

#define DM 512
#define NST 16
#define NDEPTH 8
#define NB 2
#define NL 1024
#define MROWS 2048
#define VOCAB 50257
#define VPAD  50304
#define NCH 32     // chunks along L
#define CLEN 32    // steps per chunk

typedef __attribute__((ext_vector_type(8))) short bf16x8;
typedef __attribute__((ext_vector_type(4))) float f32x4;
typedef __attribute__((ext_vector_type(8))) unsigned short ushort8;

#define AS1(p) ((const __attribute__((address_space(1))) void*)(p))
#define AS3(p) ((__attribute__((address_space(3))) void*)(p))

static __device__ __forceinline__ unsigned short f2bf(float f) {
  unsigned int x = __float_as_uint(f);
  unsigned int r = (x + 0x7FFFu + ((x >> 16) & 1u)) >> 16;
  return (unsigned short)r;
}
static __device__ __forceinline__ float bf2f(unsigned short u) {
  return __uint_as_float((unsigned int)u << 16);
}

// ---------------- embedding gather: x[b,l,:] = emb[id] (fp32) ----------------
__global__ __launch_bounds__(256) void k_gather(const int* __restrict__ ids,
    const float* __restrict__ emb, float* __restrict__ x)
{
  int gid = blockIdx.x * 256 + threadIdx.x;      // one float4 each, 2048*128
  int row = gid >> 7, c = (gid & 127) * 4;
  int id = ids[row];
  *(float4*)(x + (size_t)row * DM + c) = *(const float4*)(emb + (size_t)id * DM + c);
}

// ---------------- weight transpose+bf16: Wt[n][k] = bf16(W[k][n]) ------------
// f: 0=W_dt (into Tdtbc rows 0-511), 1..3=W_r/k/v (Trkv), 4=W_o (To)
__global__ void k_transpose(const float* __restrict__ Wdt, const float* __restrict__ Wr,
    const float* __restrict__ Wk, const float* __restrict__ Wv, const float* __restrict__ Wo,
    unsigned short* __restrict__ Tdtbc, unsigned short* __restrict__ Trkv, unsigned short* __restrict__ To)
{
  __shared__ float tile[32][33];
  int z = blockIdx.z, layer = z / 5, f = z % 5;
  const float* src;
  unsigned short* dst;
  size_t lw = (size_t)layer * DM * DM;
  if (f == 0)      { src = Wdt + lw; dst = Tdtbc + (size_t)layer * 640 * DM; }
  else if (f == 1) { src = Wr  + lw; dst = Trkv + (size_t)layer * 3 * DM * DM; }
  else if (f == 2) { src = Wk  + lw; dst = Trkv + (size_t)layer * 3 * DM * DM + DM * DM; }
  else if (f == 3) { src = Wv  + lw; dst = Trkv + (size_t)layer * 3 * DM * DM + 2 * DM * DM; }
  else             { src = Wo  + lw; dst = To   + lw; }
  int tx = threadIdx.x, ty = threadIdx.y;        // 32 x 8
  int kb = blockIdx.y * 32, nb = blockIdx.x * 32;
  #pragma unroll
  for (int i = 0; i < 4; i++)
    tile[ty + i * 8][tx] = src[(size_t)(kb + ty + i * 8) * DM + nb + tx];
  __syncthreads();
  #pragma unroll
  for (int i = 0; i < 4; i++)
    dst[(size_t)(nb + ty + i * 8) * DM + kb + tx] = f2bf(tile[tx][ty + i * 8]);
}

// -------- pack W_B|W_C transposed into Tdtbc rows 512-639 (32 real + pad) ----
__global__ __launch_bounds__(256) void k_bcpack(const float* __restrict__ WB,
    const float* __restrict__ WC, unsigned short* __restrict__ Tdtbc)
{
  int gid = blockIdx.x * 256 + threadIdx.x;      // ((layer*128)+n)*512+k
  int k = gid & 511, n = (gid >> 9) & 127, layer = gid >> 16;
  float v = 0.f;
  if (n < 16)      v = WB[((size_t)layer * DM + k) * NST + n];
  else if (n < 32) v = WC[((size_t)layer * DM + k) * NST + (n - 16)];
  Tdtbc[(size_t)layer * 640 * DM + (size_t)(512 + n) * DM + k] = f2bf(v);
}

// ---------------- emb -> bf16, padded rows zero ------------------------------
__global__ __launch_bounds__(256) void k_embcvt(const float* __restrict__ emb,
    unsigned short* __restrict__ out)
{
  int gid = blockIdx.x * 256 + threadIdx.x;      // 8 elements each
  size_t base = (size_t)gid * 8;
  int row = (int)(base >> 9);
  ushort8 o;
  if (row < VOCAB) {
    float4 a = *(const float4*)(emb + base);
    float4 b = *(const float4*)(emb + base + 4);
    o[0]=f2bf(a.x); o[1]=f2bf(a.y); o[2]=f2bf(a.z); o[3]=f2bf(a.w);
    o[4]=f2bf(b.x); o[5]=f2bf(b.y); o[6]=f2bf(b.z); o[7]=f2bf(b.w);
  } else {
    o = (ushort8)0;
  }
  *(ushort8*)(out + base) = o;
}

// ---------------- LayerNorm: wave per row, optional f32 + bf16 outputs -------
__global__ __launch_bounds__(256) void k_ln(const float* __restrict__ x,
    const float* __restrict__ g, const float* __restrict__ bb,
    float* __restrict__ of, unsigned short* __restrict__ ob)
{
  const int w = threadIdx.x >> 6, l = threadIdx.x & 63;
  const int row = blockIdx.x * 4 + w;
  const float* xr = x + (size_t)row * DM + l * 8;
  float4 v0 = *(const float4*)(xr);
  float4 v1 = *(const float4*)(xr + 4);
  float s = v0.x + v0.y + v0.z + v0.w + v1.x + v1.y + v1.z + v1.w;
  float q = v0.x*v0.x + v0.y*v0.y + v0.z*v0.z + v0.w*v0.w
          + v1.x*v1.x + v1.y*v1.y + v1.z*v1.z + v1.w*v1.w;
  #pragma unroll
  for (int m = 1; m < 64; m <<= 1) { s += __shfl_xor(s, m); q += __shfl_xor(q, m); }
  const float mu = s * (1.0f / DM);
  const float var = q * (1.0f / DM) - mu * mu;
  const float rs = rsqrtf(var + 1e-5f);
  const float4 g0 = *(const float4*)(g + l * 8);
  const float4 g1 = *(const float4*)(g + l * 8 + 4);
  const float4 b0 = *(const float4*)(bb + l * 8);
  const float4 b1 = *(const float4*)(bb + l * 8 + 4);
  float y[8];
  y[0] = (v0.x - mu) * rs * g0.x + b0.x;
  y[1] = (v0.y - mu) * rs * g0.y + b0.y;
  y[2] = (v0.z - mu) * rs * g0.z + b0.z;
  y[3] = (v0.w - mu) * rs * g0.w + b0.w;
  y[4] = (v1.x - mu) * rs * g1.x + b1.x;
  y[5] = (v1.y - mu) * rs * g1.y + b1.y;
  y[6] = (v1.z - mu) * rs * g1.z + b1.z;
  y[7] = (v1.w - mu) * rs * g1.w + b1.w;
  if (of) {
    float4 o0 = {y[0], y[1], y[2], y[3]}, o1 = {y[4], y[5], y[6], y[7]};
    *(float4*)(of + (size_t)row * DM + l * 8) = o0;
    *(float4*)(of + (size_t)row * DM + l * 8 + 4) = o1;
  }
  if (ob) {
    ushort8 o;
    #pragma unroll
    for (int j = 0; j < 8; j++) o[j] = f2bf(y[j]);
    *(ushort8*)(ob + (size_t)row * DM + l * 8) = o;
  }
}

// == layer GEMM: overlapped double-buffer 2-phase (r13 proven), BK=64, XOR swz =
// Grid-limited regime (1-1.5 blocks/CU) -> next-tile STAGE issued BEFORE the
// compute phase so global_load_lds flies under MFMA; ONE __syncthreads per
// K-tile. Statically distinct buffers (unrolled even/odd).
// EPI: 0 plain | 2 C2 += 0.5*acc | 3 fused dt(softplus+bias)/BC
template<int BM, int BN, int EPI>
__global__ __launch_bounds__(256) void gemm_bt(const unsigned short* __restrict__ A,
    const unsigned short* __restrict__ Bt, float* __restrict__ C, int N, int ldc,
    const float* __restrict__ bias, float* __restrict__ C2)
{
  constexpr int K = DM;
  constexpr int MI = BM / 32, NI = BN / 32;
  __shared__ unsigned short lsA0[BM * 64];
  __shared__ unsigned short lsA1[BM * 64];
  __shared__ unsigned short lsB0[BN * 64];
  __shared__ unsigned short lsB1[BN * 64];
  const int t = threadIdx.x;
  const int w = t >> 6, l = t & 63;
  const int wm = (w >> 1) * (BM / 2), wn = (w & 1) * (BN / 2);
  const size_t bm = (size_t)blockIdx.x * BM, bn = (size_t)blockIdx.y * BN;
  f32x4 acc[MI][NI] = {};
  const int srow = t >> 3, sslot = t & 7;       // stage: 32 rows x 8 slots per op
  const int gs = sslot ^ (srow & 7);            // pre-swizzled source slot
  const unsigned short* Ag = A + (bm + srow) * K + gs * 8;
  const unsigned short* Bg = Bt + (bn + srow) * K + gs * 8;
  const int lr = l & 15, lq = l >> 4;

#define GB_STAGE(dA, dB, kt) do {                                              \
    const int k0_ = (kt) * 64;                                                 \
    _Pragma("unroll")                                                          \
    for (int o = 0; o < BM / 32; ++o)                                          \
      __builtin_amdgcn_global_load_lds(AS1(Ag + (size_t)(o * 32) * K + k0_),   \
          AS3(dA + (o * 32 + srow) * 64 + sslot * 8), 16, 0, 0);               \
    _Pragma("unroll")                                                          \
    for (int o = 0; o < BN / 32; ++o)                                          \
      __builtin_amdgcn_global_load_lds(AS1(Bg + (size_t)(o * 32) * K + k0_),   \
          AS3(dB + (o * 32 + srow) * 64 + sslot * 8), 16, 0, 0);               \
  } while (0)

#define GB_COMPUTE(sA, sB) do {                                                \
    bf16x8 af[MI][2], bfr[NI][2];                                              \
    _Pragma("unroll")                                                          \
    for (int i = 0; i < MI; ++i) {                                             \
      int row = wm + i * 16 + lr;                                              \
      _Pragma("unroll")                                                        \
      for (int h = 0; h < 2; ++h)                                              \
        af[i][h] = *(const bf16x8*)(sA + row * 64 + (((h * 4 + lq) ^ (row & 7)) * 8)); \
    }                                                                          \
    _Pragma("unroll")                                                          \
    for (int i = 0; i < NI; ++i) {                                             \
      int row = wn + i * 16 + lr;                                              \
      _Pragma("unroll")                                                        \
      for (int h = 0; h < 2; ++h)                                              \
        bfr[i][h] = *(const bf16x8*)(sB + row * 64 + (((h * 4 + lq) ^ (row & 7)) * 8)); \
    }                                                                          \
    _Pragma("unroll")                                                          \
    for (int h = 0; h < 2; ++h)                                                \
      _Pragma("unroll")                                                        \
      for (int mi = 0; mi < MI; ++mi)                                          \
        _Pragma("unroll")                                                      \
        for (int ni = 0; ni < NI; ++ni)                                        \
          acc[mi][ni] = __builtin_amdgcn_mfma_f32_16x16x32_bf16(af[mi][h], bfr[ni][h], acc[mi][ni], 0, 0, 0); \
  } while (0)

  GB_STAGE(lsA0, lsB0, 0);
  __syncthreads();                              // buf0 ready (implicit vmcnt(0))
  #pragma unroll
  for (int kk = 0; kk < 4; ++kk) {
    GB_STAGE(lsA1, lsB1, kk * 2 + 1);           // loads fly under compute
    GB_COMPUTE(lsA0, lsB0);
    __syncthreads();                            // buf1 ready; buf0 reads done
    if (kk * 2 + 2 < 8) GB_STAGE(lsA0, lsB0, kk * 2 + 2);
    GB_COMPUTE(lsA1, lsB1);
    __syncthreads();                            // buf0 ready; buf1 reads done
  }
#undef GB_STAGE
#undef GB_COMPUTE

  const int lg = l >> 4;
  #pragma unroll
  for (int mi = 0; mi < MI; ++mi) {
    #pragma unroll
    for (int ni = 0; ni < NI; ++ni) {
      int n = (int)bn + wn + ni * 16 + lr;
      size_t m0 = bm + wm + mi * 16 + lg * 4;
      #pragma unroll
      for (int j = 0; j < 4; ++j) {
        float v = acc[mi][ni][j];
        if (EPI == 0) {
          C[(m0 + j) * (size_t)ldc + n] = v;
        } else if (EPI == 2) {
          C2[(m0 + j) * (size_t)ldc + n] += 0.5f * v;
        } else {                                // fused dt | BC
          if (n < 512) {
            float b = v + bias[n];
            C[(m0 + j) * (size_t)512 + n] = fmaxf(b, 0.f) + log1pf(__expf(-fabsf(b)));
          } else if (n < 544) {
            C2[(m0 + j) * (size_t)32 + (n - 512)] = v;
          }
        }
      }
    }
  }
}

// ===== head GEMM: 512 threads, 256x128 tile, BK=64, XCD-ownership map ========
// Measured winner of the head A/B series (225us vs 251 3-buf vs 241 dbuf):
// serial 2-phase at 48KB LDS keeps 3 blocks/CU of TLP, which beats every
// source-level pipeline for this shallow-K, write-heavy GEMM.
// Grid 3200 = 8 XCD x 400; XCD c owns n-tiles [c*50, c*50+50) with m-tile
// innermost so each B panel is fetched once per XCD and A stays L2-resident.
__global__ __launch_bounds__(512) void gemm_head(const unsigned short* __restrict__ A,
    const unsigned short* __restrict__ Bt, float* __restrict__ C)
{
  __shared__ unsigned short lsA[256 * 64];      // 32 KB
  __shared__ unsigned short lsB[128 * 64];      // 16 KB
  const int t = threadIdx.x;
  const int w = t >> 6, l = t & 63;
  const int wm = (w >> 1) * 64, wn = (w & 1) * 64;
  const int c = (int)blockIdx.x & 7, j = (int)blockIdx.x >> 3;
  const int ntile = c * 50 + (j >> 3), mtile = j & 7;
  if (ntile >= 393) return;                     // 50304/128 = 393 real n-tiles
  const size_t bm = (size_t)mtile * 256, bn = (size_t)ntile * 128;
  f32x4 acc[4][4] = {};
  const int srow = t >> 3, sslot = t & 7;       // stage: 64 rows x 8 slots per op
  const int gs = sslot ^ (srow & 7);
  const unsigned short* Ag = A + (bm + srow) * DM + gs * 8;
  const unsigned short* Bg = Bt + (bn + srow) * DM + gs * 8;
  const int lr = l & 15, lq = l >> 4;
  for (int k0 = 0; k0 < DM; k0 += 64) {
    #pragma unroll
    for (int o = 0; o < 4; ++o)
      __builtin_amdgcn_global_load_lds(AS1(Ag + (size_t)(o * 64) * DM + k0),
          AS3(lsA + (o * 64 + srow) * 64 + sslot * 8), 16, 0, 0);
    #pragma unroll
    for (int o = 0; o < 2; ++o)
      __builtin_amdgcn_global_load_lds(AS1(Bg + (size_t)(o * 64) * DM + k0),
          AS3(lsB + (o * 64 + srow) * 64 + sslot * 8), 16, 0, 0);
    asm volatile("s_waitcnt vmcnt(0)" ::: "memory");
    __syncthreads();
    bf16x8 af[4][2], bfr[4][2];
    #pragma unroll
    for (int i = 0; i < 4; ++i) {
      int row = wm + i * 16 + lr;
      #pragma unroll
      for (int h = 0; h < 2; ++h)
        af[i][h] = *(const bf16x8*)(lsA + row * 64 + (((h * 4 + lq) ^ (row & 7)) * 8));
    }
    #pragma unroll
    for (int i = 0; i < 4; ++i) {
      int row = wn + i * 16 + lr;
      #pragma unroll
      for (int h = 0; h < 2; ++h)
        bfr[i][h] = *(const bf16x8*)(lsB + row * 64 + (((h * 4 + lq) ^ (row & 7)) * 8));
    }
    #pragma unroll
    for (int h = 0; h < 2; ++h)
      #pragma unroll
      for (int mi = 0; mi < 4; ++mi)
        #pragma unroll
        for (int ni = 0; ni < 4; ++ni)
          acc[mi][ni] = __builtin_amdgcn_mfma_f32_16x16x32_bf16(af[mi][h], bfr[ni][h], acc[mi][ni], 0, 0, 0);
    __syncthreads();
  }
  const int lg = l >> 4;
  #pragma unroll
  for (int mi = 0; mi < 4; ++mi) {
    #pragma unroll
    for (int ni = 0; ni < 4; ++ni) {
      int n = (int)bn + wn + ni * 16 + lr;
      if (n >= VOCAB) continue;
      size_t m0 = bm + wm + mi * 16 + lg * 4;
      #pragma unroll
      for (int jj = 0; jj < 4; ++jj)
        C[(m0 + jj) * (size_t)VOCAB + n] = acc[mi][ni][jj];
    }
  }
}

// ============================ chunked SSM scan ===============================
__global__ __launch_bounds__(256) void k_ssm1(const float* __restrict__ dt,
    const unsigned short* __restrict__ u, const float* __restrict__ BC,
    const float* __restrict__ A_log, float* __restrict__ Pb, float* __restrict__ Sb)
{
  const int t = threadIdx.x;
  const int grp = t >> 4, n = t & 15;
  const int cg = blockIdx.x & 63, ck = blockIdx.x >> 6;   // channel-group, chunk
  const int ch = cg * 16 + grp;                           // 0..1023
  const int b = ch >> 9, d = ch & 511;
  const float A = -__expf(A_log[d * NST + n]);
  const int t0 = ck * CLEN;
  const float* dtp = dt + ((size_t)b * NL + t0) * DM + d;
  const unsigned short* up = u + ((size_t)b * NL + t0) * DM + d;
  const float* bcp = BC + ((size_t)b * NL + t0) * 32 + n;
  float P = 1.f, S = 0.f;
  #pragma unroll
  for (int tt = 0; tt < CLEN; ++tt) {
    float dtv = dtp[(size_t)tt * DM];
    float uv  = bf2f(up[(size_t)tt * DM]);
    float Bv  = bcp[(size_t)tt * 32];
    float e = __expf(dtv * A);
    S = fmaf(e, S, dtv * uv * Bv);
    P *= e;
  }
  size_t cn = (size_t)ch * NST + n;                       // 0..16383
  Pb[cn * NCH + ck] = P;
  Sb[cn * NCH + ck] = S;
}

__global__ __launch_bounds__(256) void k_ssm2(const float* __restrict__ Pb,
    const float* __restrict__ Sb, float* __restrict__ H0)
{
  const int wid = blockIdx.x * 8 + (threadIdx.x >> 5);    // channel-state 0..16383
  const int lane = threadIdx.x & 31;                      // chunk
  float coef = Pb[(size_t)wid * NCH + lane];
  float sum  = Sb[(size_t)wid * NCH + lane];
  #pragma unroll
  for (int m = 1; m < 32; m <<= 1) {
    float cr = __shfl_up(coef, m, 32);
    float sr = __shfl_up(sum, m, 32);
    if (lane >= m) { sum = fmaf(coef, sr, sum); coef *= cr; }
  }
  float hp = __shfl_up(sum, 1, 32);
  H0[(size_t)wid * NCH + lane] = (lane == 0) ? 0.f : hp;  // h at chunk entry
}

__global__ __launch_bounds__(256) void k_ssm3(const float* __restrict__ dt,
    const unsigned short* __restrict__ u, const float* __restrict__ BC,
    const float* __restrict__ A_log, const float* __restrict__ Dp,
    const float* __restrict__ H0, float* __restrict__ x)
{
  const int t = threadIdx.x;
  const int grp = t >> 4, n = t & 15;
  const int cg = blockIdx.x & 63, ck = blockIdx.x >> 6;
  const int ch = cg * 16 + grp;
  const int b = ch >> 9, d = ch & 511;
  const float A = -__expf(A_log[d * NST + n]);
  const float Dpv = Dp[d];
  const int t0 = ck * CLEN;
  const float* dtp = dt + ((size_t)b * NL + t0) * DM + d;
  const unsigned short* up = u + ((size_t)b * NL + t0) * DM + d;
  const float* bcp = BC + ((size_t)b * NL + t0) * 32 + n;
  float* xp = x + ((size_t)b * NL + t0) * DM + d;
  size_t cn = (size_t)ch * NST + n;
  float h = H0[cn * NCH + ck];
  #pragma unroll
  for (int tt = 0; tt < CLEN; ++tt) {
    float dtv = dtp[(size_t)tt * DM];
    float uv  = bf2f(up[(size_t)tt * DM]);
    float Bv  = bcp[(size_t)tt * 32];
    float Cv  = bcp[(size_t)tt * 32 + 16];
    float e = __expf(dtv * A);
    h = fmaf(e, h, dtv * uv * Bv);
    float p2 = h * Cv;
    p2 += __shfl_xor(p2, 1);
    p2 += __shfl_xor(p2, 2);
    p2 += __shfl_xor(p2, 4);
    p2 += __shfl_xor(p2, 8);
    if (n == 0) xp[(size_t)tt * DM] += 0.5f * (p2 + Dpv * uv);
  }
}

// ============================ chunked WKV scan ===============================
__global__ __launch_bounds__(256) void k_wkv1(const float* __restrict__ rkv,
    const float* __restrict__ tdec, float* __restrict__ SaB, float* __restrict__ SbB)
{
  const int gid = blockIdx.x * 256 + threadIdx.x;         // 32768
  const int ch = gid & 1023, ck = gid >> 10;
  const int b = ch >> 9, d = ch & 511;
  const float w = __expf(-__expf(tdec[d]));
  const float* base = rkv + ((size_t)b * NL + ck * CLEN) * 1536;
  float Sa = 0.f, Sb = 0.f;
  #pragma unroll
  for (int tt = 0; tt < CLEN; ++tt) {
    const float* row = base + (size_t)tt * 1536;
    float kt = row[512 + d];
    kt = fminf(30.f, fmaxf(-30.f, kt));
    float vt = row[1024 + d];
    float ek = __expf(kt);
    Sa = fmaf(w, Sa, ek * vt);
    Sb = fmaf(w, Sb, ek);
  }
  SaB[(size_t)ch * NCH + ck] = Sa;
  SbB[(size_t)ch * NCH + ck] = Sb;
}

__global__ __launch_bounds__(256) void k_wkv2(const float* __restrict__ SaB,
    const float* __restrict__ SbB, const float* __restrict__ tdec,
    float* __restrict__ HaB, float* __restrict__ HbB)
{
  const int ch = blockIdx.x * 8 + (threadIdx.x >> 5);     // 0..1023
  const int lane = threadIdx.x & 31;                      // chunk
  const int d = ch & 511;
  float coef = __expf(-32.f * __expf(tdec[d]));           // w^CLEN
  float sa = SaB[(size_t)ch * NCH + lane];
  float sb = SbB[(size_t)ch * NCH + lane];
  #pragma unroll
  for (int m = 1; m < 32; m <<= 1) {
    float cr  = __shfl_up(coef, m, 32);
    float sar = __shfl_up(sa, m, 32);
    float sbr = __shfl_up(sb, m, 32);
    if (lane >= m) { sa = fmaf(coef, sar, sa); sb = fmaf(coef, sbr, sb); coef *= cr; }
  }
  float ha = __shfl_up(sa, 1, 32);
  float hb = __shfl_up(sb, 1, 32);
  HaB[(size_t)ch * NCH + lane] = (lane == 0) ? 0.f : ha;
  HbB[(size_t)ch * NCH + lane] = (lane == 0) ? 0.f : hb;
}

__global__ __launch_bounds__(256) void k_wkv3(const float* __restrict__ rkv,
    const float* __restrict__ tdec, const float* __restrict__ tfir,
    const float* __restrict__ HaB, const float* __restrict__ HbB,
    unsigned short* __restrict__ ro)
{
  const int gid = blockIdx.x * 256 + threadIdx.x;         // 32768
  const int ch = gid & 1023, ck = gid >> 10;
  const int b = ch >> 9, d = ch & 511;
  const float w = __expf(-__expf(tdec[d]));
  const float tf = tfir[d];
  float a = HaB[(size_t)ch * NCH + ck];
  float bden = HbB[(size_t)ch * NCH + ck];
  const int t0 = ck * CLEN;
  const float* base = rkv + ((size_t)b * NL + t0) * 1536;
  unsigned short* rop = ro + ((size_t)b * NL + t0) * DM + d;
  #pragma unroll
  for (int tt = 0; tt < CLEN; ++tt) {
    const float* row = base + (size_t)tt * 1536;
    float rv = row[d];
    float kt = row[512 + d];
    kt = fminf(30.f, fmaxf(-30.f, kt));
    float vt = row[1024 + d];
    float ek = __expf(kt);
    float eu = __expf(tf + kt);
    float out = __fdividef(a + eu * vt, bden + eu + 1e-6f);
    float sig = __fdividef(1.f, 1.f + __expf(-rv));
    rop[(size_t)tt * DM] = f2bf(sig * out);
    a = fmaf(w, a, ek * vt);
    bden = fmaf(w, bden, ek);
  }
}

// ============================================================================
extern "C" void kernel_launch(void* const* d_in, const int* in_sizes, int n_in,
                              void* d_out, int out_size, void* d_ws, size_t ws_size,
                              hipStream_t stream)
{
  const int*   ids   = (const int*)d_in[0];
  const float* emb   = (const float*)d_in[1];
  const float* ln1_g = (const float*)d_in[2];
  const float* ln1_b = (const float*)d_in[3];
  const float* W_dt  = (const float*)d_in[4];
  const float* b_dt  = (const float*)d_in[5];
  const float* W_B   = (const float*)d_in[6];
  const float* W_C   = (const float*)d_in[7];
  const float* A_log = (const float*)d_in[8];
  const float* D_p   = (const float*)d_in[9];
  const float* ln2_g = (const float*)d_in[10];
  const float* ln2_b = (const float*)d_in[11];
  const float* W_r   = (const float*)d_in[12];
  const float* W_k   = (const float*)d_in[13];
  const float* W_v   = (const float*)d_in[14];
  const float* W_o   = (const float*)d_in[15];
  const float* t_dec = (const float*)d_in[16];
  const float* t_fir = (const float*)d_in[17];
  const float* lnf_g = (const float*)d_in[18];
  const float* lnf_b = (const float*)d_in[19];

  char* p = (char*)d_ws;
  float*          xres  = (float*)(p + 0);                       // 4 MB
  float*          dtb   = (float*)(p + 8388608);                 // 4 MB
  float*          rkv   = (float*)(p + 12582912);                // 12 MB
  float*          BCb   = (float*)(p + 25165824);                // 256 KB
  unsigned short* abuf  = (unsigned short*)(p + 25427968);       // 2 MB
  unsigned short* Tdtbc = (unsigned short*)(p + 27525120);       // 5 MB (8 x 640 x 512)
  unsigned short* To    = (unsigned short*)(p + 32768000);       // 4 MB
  unsigned short* Trkv  = (unsigned short*)(p + 36962304);       // 12 MB
  unsigned short* Tem   = (unsigned short*)(p + 49545216);       // 51.5 MB

  // scan scratch reuses idle regions (NCH=32):
  float* Pb  = rkv;                           // 2 MB  (rkv idle during SSM)
  float* Sb  = rkv + 524288;                  // 2 MB
  float* H0  = rkv + 1048576;                 // 2 MB
  float* SaB = dtb;                           // 128 KB each (dtb idle during WKV)
  float* SbB = dtb + 32768;
  float* HaB = dtb + 65536;
  float* HbB = dtb + 98304;

  // ---- prep ----
  k_gather<<<1024, 256, 0, stream>>>(ids, emb, xres);
  k_transpose<<<dim3(16, 16, 40), dim3(32, 8), 0, stream>>>(W_dt, W_r, W_k, W_v, W_o, Tdtbc, Trkv, To);
  k_bcpack<<<2048, 256, 0, stream>>>(W_B, W_C, Tdtbc);
  k_embcvt<<<12576, 256, 0, stream>>>(emb, Tem);

  // ---- layers ----
  for (int i = 0; i < NDEPTH; ++i) {
    k_ln<<<512, 256, 0, stream>>>(xres, ln1_g + i * DM, ln1_b + i * DM, nullptr, abuf);
    // fused: dt = softplus(u@W_dt + b_dt), BC = u@[W_B|W_C]
    gemm_bt<64, 128, 3><<<dim3(32, 5), 256, 0, stream>>>(abuf,
        Tdtbc + (size_t)i * 640 * DM, dtb, 640, 512, b_dt + i * DM, BCb);
    // chunk-parallel SSM scan (u read as bf16 from abuf)
    k_ssm1<<<2048, 256, 0, stream>>>(dtb, abuf, BCb, A_log + (size_t)i * DM * NST, Pb, Sb);
    k_ssm2<<<2048, 256, 0, stream>>>(Pb, Sb, H0);
    k_ssm3<<<2048, 256, 0, stream>>>(dtb, abuf, BCb, A_log + (size_t)i * DM * NST,
        D_p + i * DM, H0, xres);
    k_ln<<<512, 256, 0, stream>>>(xres, ln2_g + i * DM, ln2_b + i * DM, nullptr, abuf);
    gemm_bt<64, 128, 0><<<dim3(32, 12), 256, 0, stream>>>(abuf,
        Trkv + (size_t)i * 3 * DM * DM, rkv, 1536, 1536, nullptr, nullptr);
    // chunk-parallel WKV scan
    k_wkv1<<<128, 256, 0, stream>>>(rkv, t_dec + i * DM, SaB, SbB);
    k_wkv2<<<128, 256, 0, stream>>>(SaB, SbB, t_dec + i * DM, HaB, HbB);
    k_wkv3<<<128, 256, 0, stream>>>(rkv, t_dec + i * DM, t_fir + i * DM, HaB, HbB, abuf);
    gemm_bt<64, 128, 2><<<dim3(32, 4), 256, 0, stream>>>(abuf,
        To + (size_t)i * DM * DM, nullptr, 512, 512, nullptr, xres);
  }

  // ---- final LN + tied head ----
  k_ln<<<512, 256, 0, stream>>>(xres, lnf_g, lnf_b, nullptr, abuf);
  gemm_head<<<3200, 512, 0, stream>>>(abuf, Tem, (float*)d_out);
}

// Round 17
// 1096.213 us; speedup vs baseline: 1.0455x; 1.0125x over previous
//
#include <hip/hip_runtime.h>

#define DM 512
#define NST 16
#define NDEPTH 8
#define NB 2
#define NL 1024
#define MROWS 2048
#define VOCAB 50257
#define VPAD  50304
#define NCH 32     // chunks along L
#define CLEN 32    // steps per chunk

typedef __attribute__((ext_vector_type(8))) short bf16x8;
typedef __attribute__((ext_vector_type(4))) float f32x4;
typedef __attribute__((ext_vector_type(8))) unsigned short ushort8;

#define AS1(p) ((const __attribute__((address_space(1))) void*)(p))
#define AS3(p) ((__attribute__((address_space(3))) void*)(p))

static __device__ __forceinline__ unsigned short f2bf(float f) {
  unsigned int x = __float_as_uint(f);
  unsigned int r = (x + 0x7FFFu + ((x >> 16) & 1u)) >> 16;
  return (unsigned short)r;
}
static __device__ __forceinline__ float bf2f(unsigned short u) {
  return __uint_as_float((unsigned int)u << 16);
}

// ---------------- embedding gather: x[b,l,:] = emb[id] (fp32) ----------------
__global__ __launch_bounds__(256) void k_gather(const int* __restrict__ ids,
    const float* __restrict__ emb, float* __restrict__ x)
{
  int gid = blockIdx.x * 256 + threadIdx.x;      // one float4 each, 2048*128
  int row = gid >> 7, c = (gid & 127) * 4;
  int id = ids[row];
  *(float4*)(x + (size_t)row * DM + c) = *(const float4*)(emb + (size_t)id * DM + c);
}

// ---------------- weight transpose+bf16: Wt[n][k] = bf16(W[k][n]) ------------
// f: 0=W_dt (into Tdtbc rows 0-511), 1..3=W_r/k/v (Trkv), 4=W_o (To)
__global__ void k_transpose(const float* __restrict__ Wdt, const float* __restrict__ Wr,
    const float* __restrict__ Wk, const float* __restrict__ Wv, const float* __restrict__ Wo,
    unsigned short* __restrict__ Tdtbc, unsigned short* __restrict__ Trkv, unsigned short* __restrict__ To)
{
  __shared__ float tile[32][33];
  int z = blockIdx.z, layer = z / 5, f = z % 5;
  const float* src;
  unsigned short* dst;
  size_t lw = (size_t)layer * DM * DM;
  if (f == 0)      { src = Wdt + lw; dst = Tdtbc + (size_t)layer * 640 * DM; }
  else if (f == 1) { src = Wr  + lw; dst = Trkv + (size_t)layer * 3 * DM * DM; }
  else if (f == 2) { src = Wk  + lw; dst = Trkv + (size_t)layer * 3 * DM * DM + DM * DM; }
  else if (f == 3) { src = Wv  + lw; dst = Trkv + (size_t)layer * 3 * DM * DM + 2 * DM * DM; }
  else             { src = Wo  + lw; dst = To   + lw; }
  int tx = threadIdx.x, ty = threadIdx.y;        // 32 x 8
  int kb = blockIdx.y * 32, nb = blockIdx.x * 32;
  #pragma unroll
  for (int i = 0; i < 4; i++)
    tile[ty + i * 8][tx] = src[(size_t)(kb + ty + i * 8) * DM + nb + tx];
  __syncthreads();
  #pragma unroll
  for (int i = 0; i < 4; i++)
    dst[(size_t)(nb + ty + i * 8) * DM + kb + tx] = f2bf(tile[tx][ty + i * 8]);
}

// -------- pack W_B|W_C transposed into Tdtbc rows 512-639 (32 real + pad) ----
__global__ __launch_bounds__(256) void k_bcpack(const float* __restrict__ WB,
    const float* __restrict__ WC, unsigned short* __restrict__ Tdtbc)
{
  int gid = blockIdx.x * 256 + threadIdx.x;      // ((layer*128)+n)*512+k
  int k = gid & 511, n = (gid >> 9) & 127, layer = gid >> 16;
  float v = 0.f;
  if (n < 16)      v = WB[((size_t)layer * DM + k) * NST + n];
  else if (n < 32) v = WC[((size_t)layer * DM + k) * NST + (n - 16)];
  Tdtbc[(size_t)layer * 640 * DM + (size_t)(512 + n) * DM + k] = f2bf(v);
}

// ---------------- emb -> bf16, padded rows zero ------------------------------
__global__ __launch_bounds__(256) void k_embcvt(const float* __restrict__ emb,
    unsigned short* __restrict__ out)
{
  int gid = blockIdx.x * 256 + threadIdx.x;      // 8 elements each
  size_t base = (size_t)gid * 8;
  int row = (int)(base >> 9);
  ushort8 o;
  if (row < VOCAB) {
    float4 a = *(const float4*)(emb + base);
    float4 b = *(const float4*)(emb + base + 4);
    o[0]=f2bf(a.x); o[1]=f2bf(a.y); o[2]=f2bf(a.z); o[3]=f2bf(a.w);
    o[4]=f2bf(b.x); o[5]=f2bf(b.y); o[6]=f2bf(b.z); o[7]=f2bf(b.w);
  } else {
    o = (ushort8)0;
  }
  *(ushort8*)(out + base) = o;
}

// ---------------- LayerNorm: wave per row, optional f32 + bf16 outputs -------
__global__ __launch_bounds__(256) void k_ln(const float* __restrict__ x,
    const float* __restrict__ g, const float* __restrict__ bb,
    float* __restrict__ of, unsigned short* __restrict__ ob)
{
  const int w = threadIdx.x >> 6, l = threadIdx.x & 63;
  const int row = blockIdx.x * 4 + w;
  const float* xr = x + (size_t)row * DM + l * 8;
  float4 v0 = *(const float4*)(xr);
  float4 v1 = *(const float4*)(xr + 4);
  float s = v0.x + v0.y + v0.z + v0.w + v1.x + v1.y + v1.z + v1.w;
  float q = v0.x*v0.x + v0.y*v0.y + v0.z*v0.z + v0.w*v0.w
          + v1.x*v1.x + v1.y*v1.y + v1.z*v1.z + v1.w*v1.w;
  #pragma unroll
  for (int m = 1; m < 64; m <<= 1) { s += __shfl_xor(s, m); q += __shfl_xor(q, m); }
  const float mu = s * (1.0f / DM);
  const float var = q * (1.0f / DM) - mu * mu;
  const float rs = rsqrtf(var + 1e-5f);
  const float4 g0 = *(const float4*)(g + l * 8);
  const float4 g1 = *(const float4*)(g + l * 8 + 4);
  const float4 b0 = *(const float4*)(bb + l * 8);
  const float4 b1 = *(const float4*)(bb + l * 8 + 4);
  float y[8];
  y[0] = (v0.x - mu) * rs * g0.x + b0.x;
  y[1] = (v0.y - mu) * rs * g0.y + b0.y;
  y[2] = (v0.z - mu) * rs * g0.z + b0.z;
  y[3] = (v0.w - mu) * rs * g0.w + b0.w;
  y[4] = (v1.x - mu) * rs * g1.x + b1.x;
  y[5] = (v1.y - mu) * rs * g1.y + b1.y;
  y[6] = (v1.z - mu) * rs * g1.z + b1.z;
  y[7] = (v1.w - mu) * rs * g1.w + b1.w;
  if (of) {
    float4 o0 = {y[0], y[1], y[2], y[3]}, o1 = {y[4], y[5], y[6], y[7]};
    *(float4*)(of + (size_t)row * DM + l * 8) = o0;
    *(float4*)(of + (size_t)row * DM + l * 8 + 4) = o1;
  }
  if (ob) {
    ushort8 o;
    #pragma unroll
    for (int j = 0; j < 8; j++) o[j] = f2bf(y[j]);
    *(ushort8*)(ob + (size_t)row * DM + l * 8) = o;
  }
}

// == layer GEMM: overlapped double-buffer 2-phase (r13 proven), BK=64, XOR swz =
// Grid-limited regime (1-1.5 blocks/CU) -> next-tile STAGE issued BEFORE the
// compute phase so global_load_lds flies under MFMA; ONE __syncthreads per
// K-tile. Statically distinct buffers (unrolled even/odd).
// EPI: 0 plain f32 | 2 C2 += 0.5*acc | 3 fused dt(softplus+bias)/BC
//      5 plain bf16 store (C reinterpreted as ushort*)
template<int BM, int BN, int EPI>
__global__ __launch_bounds__(256) void gemm_bt(const unsigned short* __restrict__ A,
    const unsigned short* __restrict__ Bt, float* __restrict__ C, int N, int ldc,
    const float* __restrict__ bias, float* __restrict__ C2)
{
  constexpr int K = DM;
  constexpr int MI = BM / 32, NI = BN / 32;
  __shared__ unsigned short lsA0[BM * 64];
  __shared__ unsigned short lsA1[BM * 64];
  __shared__ unsigned short lsB0[BN * 64];
  __shared__ unsigned short lsB1[BN * 64];
  const int t = threadIdx.x;
  const int w = t >> 6, l = t & 63;
  const int wm = (w >> 1) * (BM / 2), wn = (w & 1) * (BN / 2);
  const size_t bm = (size_t)blockIdx.x * BM, bn = (size_t)blockIdx.y * BN;
  f32x4 acc[MI][NI] = {};
  const int srow = t >> 3, sslot = t & 7;       // stage: 32 rows x 8 slots per op
  const int gs = sslot ^ (srow & 7);            // pre-swizzled source slot
  const unsigned short* Ag = A + (bm + srow) * K + gs * 8;
  const unsigned short* Bg = Bt + (bn + srow) * K + gs * 8;
  const int lr = l & 15, lq = l >> 4;

#define GB_STAGE(dA, dB, kt) do {                                              \
    const int k0_ = (kt) * 64;                                                 \
    _Pragma("unroll")                                                          \
    for (int o = 0; o < BM / 32; ++o)                                          \
      __builtin_amdgcn_global_load_lds(AS1(Ag + (size_t)(o * 32) * K + k0_),   \
          AS3(dA + (o * 32 + srow) * 64 + sslot * 8), 16, 0, 0);               \
    _Pragma("unroll")                                                          \
    for (int o = 0; o < BN / 32; ++o)                                          \
      __builtin_amdgcn_global_load_lds(AS1(Bg + (size_t)(o * 32) * K + k0_),   \
          AS3(dB + (o * 32 + srow) * 64 + sslot * 8), 16, 0, 0);               \
  } while (0)

#define GB_COMPUTE(sA, sB) do {                                                \
    bf16x8 af[MI][2], bfr[NI][2];                                              \
    _Pragma("unroll")                                                          \
    for (int i = 0; i < MI; ++i) {                                             \
      int row = wm + i * 16 + lr;                                              \
      _Pragma("unroll")                                                        \
      for (int h = 0; h < 2; ++h)                                              \
        af[i][h] = *(const bf16x8*)(sA + row * 64 + (((h * 4 + lq) ^ (row & 7)) * 8)); \
    }                                                                          \
    _Pragma("unroll")                                                          \
    for (int i = 0; i < NI; ++i) {                                             \
      int row = wn + i * 16 + lr;                                              \
      _Pragma("unroll")                                                        \
      for (int h = 0; h < 2; ++h)                                              \
        bfr[i][h] = *(const bf16x8*)(sB + row * 64 + (((h * 4 + lq) ^ (row & 7)) * 8)); \
    }                                                                          \
    _Pragma("unroll")                                                          \
    for (int h = 0; h < 2; ++h)                                                \
      _Pragma("unroll")                                                        \
      for (int mi = 0; mi < MI; ++mi)                                          \
        _Pragma("unroll")                                                      \
        for (int ni = 0; ni < NI; ++ni)                                        \
          acc[mi][ni] = __builtin_amdgcn_mfma_f32_16x16x32_bf16(af[mi][h], bfr[ni][h], acc[mi][ni], 0, 0, 0); \
  } while (0)

  GB_STAGE(lsA0, lsB0, 0);
  __syncthreads();                              // buf0 ready (implicit vmcnt(0))
  #pragma unroll
  for (int kk = 0; kk < 4; ++kk) {
    GB_STAGE(lsA1, lsB1, kk * 2 + 1);           // loads fly under compute
    GB_COMPUTE(lsA0, lsB0);
    __syncthreads();                            // buf1 ready; buf0 reads done
    if (kk * 2 + 2 < 8) GB_STAGE(lsA0, lsB0, kk * 2 + 2);
    GB_COMPUTE(lsA1, lsB1);
    __syncthreads();                            // buf0 ready; buf1 reads done
  }
#undef GB_STAGE
#undef GB_COMPUTE

  const int lg = l >> 4;
  #pragma unroll
  for (int mi = 0; mi < MI; ++mi) {
    #pragma unroll
    for (int ni = 0; ni < NI; ++ni) {
      int n = (int)bn + wn + ni * 16 + lr;
      size_t m0 = bm + wm + mi * 16 + lg * 4;
      #pragma unroll
      for (int j = 0; j < 4; ++j) {
        float v = acc[mi][ni][j];
        if (EPI == 0) {
          C[(m0 + j) * (size_t)ldc + n] = v;
        } else if (EPI == 5) {
          ((unsigned short*)C)[(m0 + j) * (size_t)ldc + n] = f2bf(v);
        } else if (EPI == 2) {
          C2[(m0 + j) * (size_t)ldc + n] += 0.5f * v;
        } else {                                // fused dt | BC
          if (n < 512) {
            float b = v + bias[n];
            C[(m0 + j) * (size_t)512 + n] = fmaxf(b, 0.f) + log1pf(__expf(-fabsf(b)));
          } else if (n < 544) {
            C2[(m0 + j) * (size_t)32 + (n - 512)] = v;
          }
        }
      }
    }
  }
}

// ===== head GEMM: 512 threads, 256x128 tile, BK=64, XCD-ownership map ========
// Measured winner of the head A/B series (225us vs 251 3-buf vs 241 dbuf):
// serial 2-phase at 48KB LDS keeps 3 blocks/CU of TLP.
// Grid 3200 = 8 XCD x 400; XCD c owns n-tiles [c*50, c*50+50) with m-tile
// innermost so each B panel is fetched once per XCD and A stays L2-resident.
__global__ __launch_bounds__(512) void gemm_head(const unsigned short* __restrict__ A,
    const unsigned short* __restrict__ Bt, float* __restrict__ C)
{
  __shared__ unsigned short lsA[256 * 64];      // 32 KB
  __shared__ unsigned short lsB[128 * 64];      // 16 KB
  const int t = threadIdx.x;
  const int w = t >> 6, l = t & 63;
  const int wm = (w >> 1) * 64, wn = (w & 1) * 64;
  const int c = (int)blockIdx.x & 7, j = (int)blockIdx.x >> 3;
  const int ntile = c * 50 + (j >> 3), mtile = j & 7;
  if (ntile >= 393) return;                     // 50304/128 = 393 real n-tiles
  const size_t bm = (size_t)mtile * 256, bn = (size_t)ntile * 128;
  f32x4 acc[4][4] = {};
  const int srow = t >> 3, sslot = t & 7;       // stage: 64 rows x 8 slots per op
  const int gs = sslot ^ (srow & 7);
  const unsigned short* Ag = A + (bm + srow) * DM + gs * 8;
  const unsigned short* Bg = Bt + (bn + srow) * DM + gs * 8;
  const int lr = l & 15, lq = l >> 4;
  for (int k0 = 0; k0 < DM; k0 += 64) {
    #pragma unroll
    for (int o = 0; o < 4; ++o)
      __builtin_amdgcn_global_load_lds(AS1(Ag + (size_t)(o * 64) * DM + k0),
          AS3(lsA + (o * 64 + srow) * 64 + sslot * 8), 16, 0, 0);
    #pragma unroll
    for (int o = 0; o < 2; ++o)
      __builtin_amdgcn_global_load_lds(AS1(Bg + (size_t)(o * 64) * DM + k0),
          AS3(lsB + (o * 64 + srow) * 64 + sslot * 8), 16, 0, 0);
    asm volatile("s_waitcnt vmcnt(0)" ::: "memory");
    __syncthreads();
    bf16x8 af[4][2], bfr[4][2];
    #pragma unroll
    for (int i = 0; i < 4; ++i) {
      int row = wm + i * 16 + lr;
      #pragma unroll
      for (int h = 0; h < 2; ++h)
        af[i][h] = *(const bf16x8*)(lsA + row * 64 + (((h * 4 + lq) ^ (row & 7)) * 8));
    }
    #pragma unroll
    for (int i = 0; i < 4; ++i) {
      int row = wn + i * 16 + lr;
      #pragma unroll
      for (int h = 0; h < 2; ++h)
        bfr[i][h] = *(const bf16x8*)(lsB + row * 64 + (((h * 4 + lq) ^ (row & 7)) * 8));
    }
    #pragma unroll
    for (int h = 0; h < 2; ++h)
      #pragma unroll
      for (int mi = 0; mi < 4; ++mi)
        #pragma unroll
        for (int ni = 0; ni < 4; ++ni)
          acc[mi][ni] = __builtin_amdgcn_mfma_f32_16x16x32_bf16(af[mi][h], bfr[ni][h], acc[mi][ni], 0, 0, 0);
    __syncthreads();
  }
  const int lg = l >> 4;
  #pragma unroll
  for (int mi = 0; mi < 4; ++mi) {
    #pragma unroll
    for (int ni = 0; ni < 4; ++ni) {
      int n = (int)bn + wn + ni * 16 + lr;
      if (n >= VOCAB) continue;
      size_t m0 = bm + wm + mi * 16 + lg * 4;
      #pragma unroll
      for (int jj = 0; jj < 4; ++jj)
        C[(m0 + jj) * (size_t)VOCAB + n] = acc[mi][ni][jj];
    }
  }
}

// ============================ chunked SSM scan ===============================
__global__ __launch_bounds__(256) void k_ssm1(const float* __restrict__ dt,
    const unsigned short* __restrict__ u, const float* __restrict__ BC,
    const float* __restrict__ A_log, float* __restrict__ Pb, float* __restrict__ Sb)
{
  const int t = threadIdx.x;
  const int grp = t >> 4, n = t & 15;
  const int cg = blockIdx.x & 63, ck = blockIdx.x >> 6;   // channel-group, chunk
  const int ch = cg * 16 + grp;                           // 0..1023
  const int b = ch >> 9, d = ch & 511;
  const float A = -__expf(A_log[d * NST + n]);
  const int t0 = ck * CLEN;
  const float* dtp = dt + ((size_t)b * NL + t0) * DM + d;
  const unsigned short* up = u + ((size_t)b * NL + t0) * DM + d;
  const float* bcp = BC + ((size_t)b * NL + t0) * 32 + n;
  float P = 1.f, S = 0.f;
  #pragma unroll
  for (int tt = 0; tt < CLEN; ++tt) {
    float dtv = dtp[(size_t)tt * DM];
    float uv  = bf2f(up[(size_t)tt * DM]);
    float Bv  = bcp[(size_t)tt * 32];
    float e = __expf(dtv * A);
    S = fmaf(e, S, dtv * uv * Bv);
    P *= e;
  }
  size_t cn = (size_t)ch * NST + n;                       // 0..16383
  Pb[cn * NCH + ck] = P;
  Sb[cn * NCH + ck] = S;
}

__global__ __launch_bounds__(256) void k_ssm2(const float* __restrict__ Pb,
    const float* __restrict__ Sb, float* __restrict__ H0)
{
  const int wid = blockIdx.x * 8 + (threadIdx.x >> 5);    // channel-state 0..16383
  const int lane = threadIdx.x & 31;                      // chunk
  float coef = Pb[(size_t)wid * NCH + lane];
  float sum  = Sb[(size_t)wid * NCH + lane];
  #pragma unroll
  for (int m = 1; m < 32; m <<= 1) {
    float cr = __shfl_up(coef, m, 32);
    float sr = __shfl_up(sum, m, 32);
    if (lane >= m) { sum = fmaf(coef, sr, sum); coef *= cr; }
  }
  float hp = __shfl_up(sum, 1, 32);
  H0[(size_t)wid * NCH + lane] = (lane == 0) ? 0.f : hp;  // h at chunk entry
}

__global__ __launch_bounds__(256) void k_ssm3(const float* __restrict__ dt,
    const unsigned short* __restrict__ u, const float* __restrict__ BC,
    const float* __restrict__ A_log, const float* __restrict__ Dp,
    const float* __restrict__ H0, float* __restrict__ x)
{
  const int t = threadIdx.x;
  const int grp = t >> 4, n = t & 15;
  const int cg = blockIdx.x & 63, ck = blockIdx.x >> 6;
  const int ch = cg * 16 + grp;
  const int b = ch >> 9, d = ch & 511;
  const float A = -__expf(A_log[d * NST + n]);
  const float Dpv = Dp[d];
  const int t0 = ck * CLEN;
  const float* dtp = dt + ((size_t)b * NL + t0) * DM + d;
  const unsigned short* up = u + ((size_t)b * NL + t0) * DM + d;
  const float* bcp = BC + ((size_t)b * NL + t0) * 32 + n;
  float* xp = x + ((size_t)b * NL + t0) * DM + d;
  size_t cn = (size_t)ch * NST + n;
  float h = H0[cn * NCH + ck];
  #pragma unroll
  for (int tt = 0; tt < CLEN; ++tt) {
    float dtv = dtp[(size_t)tt * DM];
    float uv  = bf2f(up[(size_t)tt * DM]);
    float Bv  = bcp[(size_t)tt * 32];
    float Cv  = bcp[(size_t)tt * 32 + 16];
    float e = __expf(dtv * A);
    h = fmaf(e, h, dtv * uv * Bv);
    float p2 = h * Cv;
    p2 += __shfl_xor(p2, 1);
    p2 += __shfl_xor(p2, 2);
    p2 += __shfl_xor(p2, 4);
    p2 += __shfl_xor(p2, 8);
    if (n == 0) xp[(size_t)tt * DM] += 0.5f * (p2 + Dpv * uv);
  }
}

// ============================ chunked WKV scan (rkv in bf16) =================
__global__ __launch_bounds__(256) void k_wkv1(const unsigned short* __restrict__ rkv,
    const float* __restrict__ tdec, float* __restrict__ SaB, float* __restrict__ SbB)
{
  const int gid = blockIdx.x * 256 + threadIdx.x;         // 32768
  const int ch = gid & 1023, ck = gid >> 10;
  const int b = ch >> 9, d = ch & 511;
  const float w = __expf(-__expf(tdec[d]));
  const unsigned short* base = rkv + ((size_t)b * NL + ck * CLEN) * 1536;
  float Sa = 0.f, Sb = 0.f;
  #pragma unroll
  for (int tt = 0; tt < CLEN; ++tt) {
    const unsigned short* row = base + (size_t)tt * 1536;
    float kt = bf2f(row[512 + d]);
    kt = fminf(30.f, fmaxf(-30.f, kt));
    float vt = bf2f(row[1024 + d]);
    float ek = __expf(kt);
    Sa = fmaf(w, Sa, ek * vt);
    Sb = fmaf(w, Sb, ek);
  }
  SaB[(size_t)ch * NCH + ck] = Sa;
  SbB[(size_t)ch * NCH + ck] = Sb;
}

__global__ __launch_bounds__(256) void k_wkv2(const float* __restrict__ SaB,
    const float* __restrict__ SbB, const float* __restrict__ tdec,
    float* __restrict__ HaB, float* __restrict__ HbB)
{
  const int ch = blockIdx.x * 8 + (threadIdx.x >> 5);     // 0..1023
  const int lane = threadIdx.x & 31;                      // chunk
  const int d = ch & 511;
  float coef = __expf(-32.f * __expf(tdec[d]));           // w^CLEN
  float sa = SaB[(size_t)ch * NCH + lane];
  float sb = SbB[(size_t)ch * NCH + lane];
  #pragma unroll
  for (int m = 1; m < 32; m <<= 1) {
    float cr  = __shfl_up(coef, m, 32);
    float sar = __shfl_up(sa, m, 32);
    float sbr = __shfl_up(sb, m, 32);
    if (lane >= m) { sa = fmaf(coef, sar, sa); sb = fmaf(coef, sbr, sb); coef *= cr; }
  }
  float ha = __shfl_up(sa, 1, 32);
  float hb = __shfl_up(sb, 1, 32);
  HaB[(size_t)ch * NCH + lane] = (lane == 0) ? 0.f : ha;
  HbB[(size_t)ch * NCH + lane] = (lane == 0) ? 0.f : hb;
}

__global__ __launch_bounds__(256) void k_wkv3(const unsigned short* __restrict__ rkv,
    const float* __restrict__ tdec, const float* __restrict__ tfir,
    const float* __restrict__ HaB, const float* __restrict__ HbB,
    unsigned short* __restrict__ ro)
{
  const int gid = blockIdx.x * 256 + threadIdx.x;         // 32768
  const int ch = gid & 1023, ck = gid >> 10;
  const int b = ch >> 9, d = ch & 511;
  const float w = __expf(-__expf(tdec[d]));
  const float tf = tfir[d];
  float a = HaB[(size_t)ch * NCH + ck];
  float bden = HbB[(size_t)ch * NCH + ck];
  const int t0 = ck * CLEN;
  const unsigned short* base = rkv + ((size_t)b * NL + t0) * 1536;
  unsigned short* rop = ro + ((size_t)b * NL + t0) * DM + d;
  #pragma unroll
  for (int tt = 0; tt < CLEN; ++tt) {
    const unsigned short* row = base + (size_t)tt * 1536;
    float rv = bf2f(row[d]);
    float kt = bf2f(row[512 + d]);
    kt = fminf(30.f, fmaxf(-30.f, kt));
    float vt = bf2f(row[1024 + d]);
    float ek = __expf(kt);
    float eu = __expf(tf + kt);
    float out = __fdividef(a + eu * vt, bden + eu + 1e-6f);
    float sig = __fdividef(1.f, 1.f + __expf(-rv));
    rop[(size_t)tt * DM] = f2bf(sig * out);
    a = fmaf(w, a, ek * vt);
    bden = fmaf(w, bden, ek);
  }
}

// ============================================================================
extern "C" void kernel_launch(void* const* d_in, const int* in_sizes, int n_in,
                              void* d_out, int out_size, void* d_ws, size_t ws_size,
                              hipStream_t stream)
{
  const int*   ids   = (const int*)d_in[0];
  const float* emb   = (const float*)d_in[1];
  const float* ln1_g = (const float*)d_in[2];
  const float* ln1_b = (const float*)d_in[3];
  const float* W_dt  = (const float*)d_in[4];
  const float* b_dt  = (const float*)d_in[5];
  const float* W_B   = (const float*)d_in[6];
  const float* W_C   = (const float*)d_in[7];
  const float* A_log = (const float*)d_in[8];
  const float* D_p   = (const float*)d_in[9];
  const float* ln2_g = (const float*)d_in[10];
  const float* ln2_b = (const float*)d_in[11];
  const float* W_r   = (const float*)d_in[12];
  const float* W_k   = (const float*)d_in[13];
  const float* W_v   = (const float*)d_in[14];
  const float* W_o   = (const float*)d_in[15];
  const float* t_dec = (const float*)d_in[16];
  const float* t_fir = (const float*)d_in[17];
  const float* lnf_g = (const float*)d_in[18];
  const float* lnf_b = (const float*)d_in[19];

  char* p = (char*)d_ws;
  float*          xres  = (float*)(p + 0);                       // 4 MB
  float*          dtb   = (float*)(p + 8388608);                 // 4 MB
  float*          rkvf  = (float*)(p + 12582912);                // 12 MB region
  unsigned short* rkv   = (unsigned short*)(p + 12582912);       // bf16 rkv (6 MB)
  float*          BCb   = (float*)(p + 25165824);                // 256 KB
  unsigned short* abuf  = (unsigned short*)(p + 25427968);       // 2 MB
  unsigned short* Tdtbc = (unsigned short*)(p + 27525120);       // 5 MB (8 x 640 x 512)
  unsigned short* To    = (unsigned short*)(p + 32768000);       // 4 MB
  unsigned short* Trkv  = (unsigned short*)(p + 36962304);       // 12 MB
  unsigned short* Tem   = (unsigned short*)(p + 49545216);       // 51.5 MB

  // scan scratch reuses idle regions (NCH=32):
  float* Pb  = rkvf + 1572864;                // 2 MB  (upper rkv region idle in SSM)
  float* Sb  = rkvf + 2097152;                // 2 MB
  float* H0  = rkvf + 2621440;                // 2 MB
  float* SaB = dtb;                           // 128 KB each (dtb idle during WKV)
  float* SbB = dtb + 32768;
  float* HaB = dtb + 65536;
  float* HbB = dtb + 98304;

  // ---- prep ----
  k_gather<<<1024, 256, 0, stream>>>(ids, emb, xres);
  k_transpose<<<dim3(16, 16, 40), dim3(32, 8), 0, stream>>>(W_dt, W_r, W_k, W_v, W_o, Tdtbc, Trkv, To);
  k_bcpack<<<2048, 256, 0, stream>>>(W_B, W_C, Tdtbc);
  k_embcvt<<<12576, 256, 0, stream>>>(emb, Tem);

  // ---- layers ----
  for (int i = 0; i < NDEPTH; ++i) {
    k_ln<<<512, 256, 0, stream>>>(xres, ln1_g + i * DM, ln1_b + i * DM, nullptr, abuf);
    // fused: dt = softplus(u@W_dt + b_dt), BC = u@[W_B|W_C]
    gemm_bt<64, 128, 3><<<dim3(32, 5), 256, 0, stream>>>(abuf,
        Tdtbc + (size_t)i * 640 * DM, dtb, 640, 512, b_dt + i * DM, BCb);
    // chunk-parallel SSM scan (u read as bf16 from abuf)
    k_ssm1<<<2048, 256, 0, stream>>>(dtb, abuf, BCb, A_log + (size_t)i * DM * NST, Pb, Sb);
    k_ssm2<<<2048, 256, 0, stream>>>(Pb, Sb, H0);
    k_ssm3<<<2048, 256, 0, stream>>>(dtb, abuf, BCb, A_log + (size_t)i * DM * NST,
        D_p + i * DM, H0, xres);
    k_ln<<<512, 256, 0, stream>>>(xres, ln2_g + i * DM, ln2_b + i * DM, nullptr, abuf);
    // rkv GEMM -> bf16 output (EPI=5)
    gemm_bt<64, 128, 5><<<dim3(32, 12), 256, 0, stream>>>(abuf,
        Trkv + (size_t)i * 3 * DM * DM, (float*)rkv, 1536, 1536, nullptr, nullptr);
    // chunk-parallel WKV scan (bf16 rkv)
    k_wkv1<<<128, 256, 0, stream>>>(rkv, t_dec + i * DM, SaB, SbB);
    k_wkv2<<<128, 256, 0, stream>>>(SaB, SbB, t_dec + i * DM, HaB, HbB);
    k_wkv3<<<128, 256, 0, stream>>>(rkv, t_dec + i * DM, t_fir + i * DM, HaB, HbB, abuf);
    gemm_bt<64, 128, 2><<<dim3(32, 4), 256, 0, stream>>>(abuf,
        To + (size_t)i * DM * DM, nullptr, 512, 512, nullptr, xres);
  }

  // ---- final LN + tied head ----
  k_ln<<<512, 256, 0, stream>>>(xres, lnf_g, lnf_b, nullptr, abuf);
  gemm_head<<<3200, 512, 0, stream>>>(abuf, Tem, (float*)d_out);
}